// Round 2
// baseline (419.362 us; speedup 1.0000x reference)
//
#include <hip/hip_runtime.h>
#include <stdint.h>

#define N_  8
#define CK  128
#define CV  512
#define HW  900     // 30*30 queries
#define M_  7200    // 8*30*30 memory slots
#define QK_SCALE 0.08838834764831845f  // 1/sqrt(128)

typedef __attribute__((ext_vector_type(8))) short  short8;
typedef __attribute__((ext_vector_type(4))) float  floatx4;
typedef __attribute__((ext_vector_type(4))) unsigned int   uintx4;
typedef __attribute__((ext_vector_type(4))) unsigned short ushortx4;

__device__ __forceinline__ uint16_t f32_to_bf16(float x) {
    union { float f; uint32_t u; } v; v.f = x;
    return (uint16_t)((v.u + 0x7FFFu + ((v.u >> 16) & 1u)) >> 16);
}

// Direct HBM -> LDS DMA, 16 B per lane. LDS dest is wave-uniform base
// (hardware adds lane*16B); global src is per-lane.
__device__ __forceinline__ void gload_lds16(const uint16_t* g, short* l) {
    __builtin_amdgcn_global_load_lds(
        (const __attribute__((address_space(1))) void*)g,
        (__attribute__((address_space(3))) void*)l,
        16, 0, 0);
}

// ---------------------------------------------------------------- zero dsum
__global__ void k_zero(float* __restrict__ p) {
    int i = blockIdx.x * 256 + threadIdx.x;
    if (i < N_ * M_) p[i] = 0.f;
}

// ---------------------------------------------------------------- q_val copy (channels 0..511)
__global__ __launch_bounds__(256) void k_copy_qval(const float* __restrict__ qv,
                                                   float* __restrict__ out) {
    unsigned i = blockIdx.x * 256 + threadIdx.x;
    unsigned e = i * 4u;
    unsigned n = e / (CV * HW);
    unsigned off = e - n * (CV * HW);
    *(floatx4*)&out[(size_t)n * (2 * CV * HW) + off] = *(const floatx4*)&qv[e];
}

// ---------------------------------------------------------------- transpose [N][CK][L] fp32 -> [N][L][CK] bf16
__global__ __launch_bounds__(256) void k_trans(const float* __restrict__ in,
                                               uint16_t* __restrict__ outp, int L) {
    __shared__ float tile[32][33];
    const int tx = threadIdx.x & 31;
    const int ty = threadIdx.x >> 5;      // 0..7
    const int l0 = blockIdx.x * 32;
    const int c0 = blockIdx.y * 32;
    const int n  = blockIdx.z;
    const float* src = in + (size_t)n * CK * L;
    uint16_t* dst = outp + (size_t)n * L * CK;
#pragma unroll
    for (int p = 0; p < 4; p++) {
        int c = c0 + p * 8 + ty;
        int l = l0 + tx;
        float v = 0.f;
        if (l < L) v = src[(size_t)c * L + l];
        tile[p * 8 + ty][tx] = v;
    }
    __syncthreads();
#pragma unroll
    for (int p = 0; p < 4; p++) {
        int l = l0 + p * 8 + ty;
        int c = c0 + tx;
        if (l < L) dst[(size_t)l * CK + c] = f32_to_bf16(tile[tx][p * 8 + ty]);
    }
}

// ---------------------------------------------------------------- K1: aff = qkT mkT^T, exp, colsum
// 2-phase double-buffered staging (BK=32) via global_load_lds width=16.
// Linear [128][32] LDS tiles: 64B row stride -> a wave's ds_read_b128 addresses
// (fr*64 + quad*16) tile a dense 1KB region = conflict-free.
// smem layout: [0,16384) = A0|A1|B0|B1 staging (4096 shorts each);
// whole 18432 reused as 128x144 C-tile in the epilogue.
#define K1_TS 144   // C-tile stride (shorts)

__global__ __launch_bounds__(256) void k1_gemm_exp(
    const uint16_t* __restrict__ qkT,  // [N][HW][CK] bf16 (A: rows q, k=c)
    const uint16_t* __restrict__ mkT,  // [N][M][CK] bf16  (B: rows m, k=c)
    uint16_t* __restrict__ E,          // [N][HW][M] bf16 = exp(aff*scale)
    float* __restrict__ dsum)          // [N][M]
{
    __shared__ __align__(16) short smem[18432];
    __shared__ float colsum[128];

    // XCD swizzle: 3648 blocks, 456/XCD = exactly one n-plane per XCD
    // (qkT+mkT slice = 2.1 MB -> L2-resident).
    const int bid = blockIdx.x + 57 * (blockIdx.y + 8 * blockIdx.z);
    const int swz = (bid & 7) * 456 + (bid >> 3);
    const int mb   = swz % 57;
    const int rest = swz / 57;
    const int m0 = mb * 128;
    const int q0 = (rest & 7) * 128;
    const int n  = rest >> 3;
    const int tid = threadIdx.x;

    if (tid < 128) colsum[tid] = 0.f;

    const int lane = tid & 63;
    const int wid  = tid >> 6;
    const int wq   = (wid >> 1) << 6;
    const int wm   = (wid & 1) << 6;
    const int fr   = lane & 15;
    const int quad = lane >> 4;

    // staging geometry: 8 chunks/operand of 1KB (16 rows x 32 cols bf16);
    // wave wid owns chunks {2*wid, 2*wid+1} of A and of B.
    const int ca = wid * 2;
    const int rr = lane >> 2;        // row within chunk 0..15
    const int cc = (lane & 3) * 8;   // col (shorts), 16B aligned

    const uint16_t* Ab = qkT + (size_t)n * HW * CK;
    const uint16_t* Bb = mkT + (size_t)n * M_ * CK;
    const uint16_t* A0p = Ab + (size_t)(q0 + ca * 16 + rr) * CK + cc;
    const uint16_t* A1p = A0p + 16 * CK;
    const uint16_t* B0p = Bb + (size_t)(m0 + ca * 16 + rr) * CK + cc;
    const uint16_t* B1p = B0p + 16 * CK;

    floatx4 acc[4][4];
#pragma unroll
    for (int a = 0; a < 4; a++)
#pragma unroll
        for (int b = 0; b < 4; b++) acc[a][b] = (floatx4){0.f, 0.f, 0.f, 0.f};

#define K1_STAGE(buf, ko) do { \
    gload_lds16(A0p + (ko), smem + (buf) * 4096 + ca * 512); \
    gload_lds16(A1p + (ko), smem + (buf) * 4096 + ca * 512 + 512); \
    gload_lds16(B0p + (ko), smem + 8192 + (buf) * 4096 + ca * 512); \
    gload_lds16(B1p + (ko), smem + 8192 + (buf) * 4096 + ca * 512 + 512); \
} while (0)

#define K1_COMPUTE(buf) do { \
    const int k0 = quad * 8; \
    short8 af[4], bfr[4]; \
    _Pragma("unroll") \
    for (int t = 0; t < 4; t++) \
        af[t] = *(const short8*)&smem[(buf) * 4096 + (wq + t * 16 + fr) * 32 + k0]; \
    _Pragma("unroll") \
    for (int t = 0; t < 4; t++) \
        bfr[t] = *(const short8*)&smem[8192 + (buf) * 4096 + (wm + t * 16 + fr) * 32 + k0]; \
    _Pragma("unroll") \
    for (int tq = 0; tq < 4; tq++) \
        _Pragma("unroll") \
        for (int tm = 0; tm < 4; tm++) \
            acc[tq][tm] = __builtin_amdgcn_mfma_f32_16x16x32_bf16( \
                af[tq], bfr[tm], acc[tq][tm], 0, 0, 0); \
} while (0)

    // 2-phase pipeline over 4 K-steps (CK=128, BK=32)
    K1_STAGE(0, 0);
    __syncthreads();
    K1_STAGE(1, 32); K1_COMPUTE(0); __syncthreads();
    K1_STAGE(0, 64); K1_COMPUTE(1); __syncthreads();
    K1_STAGE(1, 96); K1_COMPUTE(0); __syncthreads();
    K1_COMPUTE(1);

    // ---- epilogue phase A: exp -> LDS C-tile (stride 144), colsum
    __syncthreads();   // all frag reads done; smem reusable as C-tile
    float cs[4] = {0.f, 0.f, 0.f, 0.f};
#pragma unroll
    for (int tq = 0; tq < 4; tq++) {
#pragma unroll
        for (int tm = 0; tm < 4; tm++) {
            const int col = wm + tm * 16 + fr;
#pragma unroll
            for (int i = 0; i < 4; i++) {
                const int row = wq + tq * 16 + quad * 4 + i;
                float e = __expf(acc[tq][tm][i] * QK_SCALE);
                if (q0 + row < HW) cs[tm] += e;   // guard: padded q-rows must not pollute colsum
                smem[row * K1_TS + col] = (short)f32_to_bf16(e);
            }
        }
    }
#pragma unroll
    for (int tm = 0; tm < 4; tm++) {
        float s = cs[tm];
        s += __shfl_xor(s, 16, 64);
        s += __shfl_xor(s, 32, 64);
        if (quad == 0) atomicAdd(&colsum[wm + tm * 16 + fr], s);
    }
    __syncthreads();   // C-tile complete + colsum complete

    // ---- epilogue phase B: coalesced uint4 E-writes (8 per thread)
    uint16_t* En = E + (size_t)n * HW * M_;
#pragma unroll
    for (int j = 0; j < 8; j++) {
        int idx = tid + j * 256;       // 0..2047 = 128 rows x 16 uint4
        int r   = idx >> 4;
        int c8  = (idx & 15) * 8;      // short offset in row
        if (q0 + r < HW && m0 + c8 + 8 <= M_) {
            uintx4 v = *(const uintx4*)&smem[r * K1_TS + c8];
            *(uintx4*)&En[(size_t)(q0 + r) * M_ + m0 + c8] = v;
        }
    }
    if (tid < 128) {
        const int gm = m0 + tid;
        if (gm < M_) atomicAdd(&dsum[(size_t)n * M_ + gm], colsum[tid]);
    }
#undef K1_STAGE
#undef K1_COMPUTE
}

// ---------------------------------------------------------------- dinv = 1/d
__global__ void k_dinv(const float* __restrict__ d, float* __restrict__ di) {
    int i = blockIdx.x * 256 + threadIdx.x;
    if (i < N_ * M_) di[i] = 1.0f / d[i];
}

// ---------------------------------------------------------------- mvs = bf16(mv * dinv[m])
__global__ __launch_bounds__(256) void k_mvs(
    const float* __restrict__ mval,   // [N][CV][M]
    const float* __restrict__ dinv,   // [N][M]
    uint16_t* __restrict__ mvs)       // [N][CV][M]
{
    unsigned i = blockIdx.x * 256 + threadIdx.x;
    unsigned base = i * 4u;
    unsigned n = base / (unsigned)(CV * M_);
    unsigned m = base % (unsigned)M_;
    floatx4 v  = *(const floatx4*)&mval[base];
    floatx4 di = *(const floatx4*)&dinv[n * (unsigned)M_ + m];
    ushortx4 o;
    o[0] = f32_to_bf16(v[0] * di[0]);
    o[1] = f32_to_bf16(v[1] * di[1]);
    o[2] = f32_to_bf16(v[2] * di[2]);
    o[3] = f32_to_bf16(v[3] * di[3]);
    *(ushortx4*)&mvs[base] = o;
}

// ---------------------------------------------------------------- K2 split x3
// 2-phase double-buffered (BK=32) out = mvs . E^T over K=2400 per split.
// LDS 32 KB: A0|A1|B0|B1 (4096 shorts each), linear 64B-row tiles
// (dense conflict-free ds_read_b128). One __syncthreads (vmcnt0+barrier)
// per K-step; next tile's loads in flight under current tile's MFMA.
#define K2_SPLITS 3
#define K2_BK 32
#define K2_STEPS 75   // 2400 / 32

__global__ __launch_bounds__(256) void k2_split3(
    const uint16_t* __restrict__ mvs,  // [N][CV][M] bf16
    const uint16_t* __restrict__ E,    // [N][HW][M] bf16
    float* __restrict__ partials)      // [3][N][CV][HW]
{
    __shared__ __align__(16) short lds2[16384];

    // XCD swizzle: 768 blocks, 96/XCD (bijective, 768%8==0); consecutive ids
    // share (n,split) planes -> E/mvs panel reuse lands in the same L2.
    const int bid = blockIdx.x + 8 * (blockIdx.y + 4 * blockIdx.z);
    const int swz = (bid & 7) * 96 + (bid >> 3);
    const int q0 = (swz & 7) << 7;
    const int c0 = ((swz >> 3) & 3) << 7;
    const int nz = swz >> 5;
    const int n     = nz / K2_SPLITS;
    const int split = nz - n * K2_SPLITS;
    const int tid = threadIdx.x;

    const int lane = tid & 63;
    const int wid  = tid >> 6;
    const int wc   = (wid >> 1) << 6;
    const int wq   = (wid & 1) << 6;
    const int fr   = lane & 15;
    const int quad = lane >> 4;

    // staging geometry: 8 chunks/operand of 1KB (16 rows x 32 cols bf16);
    // wave wid owns chunks {2*wid, 2*wid+1} of A and of B.
    const int ca = wid * 2;
    const int rr = lane >> 2;
    const int cc = (lane & 3) * 8;

    const uint16_t* Asrc = mvs + (size_t)(n * CV + c0) * M_ + split * 2400;
    const uint16_t* Bsrc = E + (size_t)n * HW * M_ + split * 2400;
    const uint16_t* A0p = Asrc + (size_t)(ca * 16 + rr) * M_ + cc;
    const uint16_t* A1p = A0p + (size_t)16 * M_;
    const uint16_t* B0p = Bsrc + (size_t)(q0 + ca * 16 + rr) * M_ + cc;
    const uint16_t* B1p = B0p + (size_t)16 * M_;

    floatx4 acc[4][4];
#pragma unroll
    for (int a = 0; a < 4; a++)
#pragma unroll
        for (int b = 0; b < 4; b++) acc[a][b] = (floatx4){0.f, 0.f, 0.f, 0.f};

#define K2_STAGE(buf, mo) do { \
    gload_lds16(A0p + (mo), lds2 + (buf) * 4096 + ca * 512); \
    gload_lds16(A1p + (mo), lds2 + (buf) * 4096 + ca * 512 + 512); \
    gload_lds16(B0p + (mo), lds2 + 8192 + (buf) * 4096 + ca * 512); \
    gload_lds16(B1p + (mo), lds2 + 8192 + (buf) * 4096 + ca * 512 + 512); \
} while (0)

#define K2_COMPUTE(buf) do { \
    const int k0 = quad * 8; \
    short8 af[4], bfr[4]; \
    _Pragma("unroll") \
    for (int t = 0; t < 4; t++) \
        af[t] = *(const short8*)&lds2[(buf) * 4096 + (wc + t * 16 + fr) * 32 + k0]; \
    _Pragma("unroll") \
    for (int t = 0; t < 4; t++) \
        bfr[t] = *(const short8*)&lds2[8192 + (buf) * 4096 + (wq + t * 16 + fr) * 32 + k0]; \
    _Pragma("unroll") \
    for (int tc = 0; tc < 4; tc++) \
        _Pragma("unroll") \
        for (int tq = 0; tq < 4; tq++) \
            acc[tc][tq] = __builtin_amdgcn_mfma_f32_16x16x32_bf16( \
                af[tc], bfr[tq], acc[tc][tq], 0, 0, 0); \
} while (0)

    K2_STAGE(0, 0);
    __syncthreads();
    for (int s = 0; s < K2_STEPS - 1; s += 2) {
        K2_STAGE(1, (s + 1) * K2_BK);
        K2_COMPUTE(0);
        __syncthreads();
        K2_STAGE(0, (s + 2) * K2_BK);
        K2_COMPUTE(1);
        __syncthreads();
    }
    K2_COMPUTE(0);   // step 74 (even -> buf0)

    float* P = partials + ((size_t)split * N_ + n) * CV * HW;
#pragma unroll
    for (int tc = 0; tc < 4; tc++) {
#pragma unroll
        for (int tq = 0; tq < 4; tq++) {
            const int gq = q0 + wq + tq * 16 + fr;
            if (gq < HW) {
#pragma unroll
                for (int i = 0; i < 4; i++) {
                    const int gc = c0 + wc + tc * 16 + quad * 4 + i;
                    P[(size_t)gc * HW + gq] = acc[tc][tq][i];
                }
            }
        }
    }
#undef K2_STAGE
#undef K2_COMPUTE
}

// ---------------------------------------------------------------- reduce 3 partials -> out mapped half
__global__ __launch_bounds__(256) void k_reduce3(const float* __restrict__ partials,
                                                 float* __restrict__ out) {
    unsigned i = blockIdx.x * 256 + threadIdx.x;
    unsigned e = i * 4u;
    unsigned n = e / (CV * HW);
    unsigned off = e - n * (CV * HW);
    const size_t stride = (size_t)N_ * CV * HW;
    const float* p = partials + (size_t)n * CV * HW + off;
    floatx4 a = *(const floatx4*)&p[0];
    floatx4 b = *(const floatx4*)&p[stride];
    floatx4 c = *(const floatx4*)&p[2 * stride];
    floatx4 s = a + b + c;
    *(floatx4*)&out[(size_t)n * (2 * CV * HW) + CV * HW + off] = s;
}

// ----------------------------------------------------------------
extern "C" void kernel_launch(void* const* d_in, const int* in_sizes, int n_in,
                              void* d_out, int out_size, void* d_ws, size_t ws_size,
                              hipStream_t stream) {
    const float* qkey = (const float*)d_in[0];  // [8][128][900]
    const float* qval = (const float*)d_in[1];  // [8][512][900]
    const float* mkey = (const float*)d_in[2];  // [8][128][7200]
    const float* mval = (const float*)d_in[3];  // [8][512][7200]
    float* out = (float*)d_out;                 // [8][1024][900]

    char* ws = (char*)d_ws;
    // E 103,680,000 | dsum 230,400 | dinv 230,400 | mvs 58,982,400 | partials 44,236,800 = 207,360,000
    // qkT/mkT alias partials (dead before k2_split3 writes partials).
    uint16_t* E        = (uint16_t*)ws;
    float*    dsum     = (float*)(ws + 103680000);
    float*    dinv     = (float*)(ws + 103910400);
    uint16_t* mvs      = (uint16_t*)(ws + 104140800);
    float*    partials = (float*)(ws + 163123200);
    uint16_t* qkT      = (uint16_t*)(ws + 163123200);
    uint16_t* mkT      = (uint16_t*)(ws + 163123200 + 1843200);

    (void)in_sizes; (void)n_in; (void)out_size; (void)ws_size;

    k_zero<<<dim3((N_ * M_ + 255) / 256), 256, 0, stream>>>(dsum);
    k_copy_qval<<<dim3((N_ * CV * HW) / 4 / 256), 256, 0, stream>>>(qval, out);
    k_trans<<<dim3(29, 4, N_), 256, 0, stream>>>(qkey, qkT, HW);
    k_trans<<<dim3(225, 4, N_), 256, 0, stream>>>(mkey, mkT, M_);
    k1_gemm_exp<<<dim3(57, 8, N_), 256, 0, stream>>>(qkT, mkT, E, dsum);
    k_dinv<<<dim3((N_ * M_ + 255) / 256), 256, 0, stream>>>(dsum, dinv);
    k_mvs<<<dim3((N_ * CV * M_) / 4 / 256), 256, 0, stream>>>(mval, dinv, mvs);
    k2_split3<<<dim3(8, 4, N_ * K2_SPLITS), 256, 0, stream>>>(mvs, E, partials);
    k_reduce3<<<dim3((N_ * CV * HW) / 4 / 256), 256, 0, stream>>>(partials, out);
}

// Round 4
// 414.759 us; speedup vs baseline: 1.0111x; 1.0111x over previous
//
#include <hip/hip_runtime.h>
#include <stdint.h>

#define N_  8
#define CK  128
#define CV  512
#define HW  900     // 30*30 queries
#define M_  7200    // 8*30*30 memory slots
#define QK_SCALE 0.08838834764831845f  // 1/sqrt(128)

typedef __attribute__((ext_vector_type(8))) short  short8;
typedef __attribute__((ext_vector_type(4))) float  floatx4;
typedef __attribute__((ext_vector_type(4))) unsigned int   uintx4;
typedef __attribute__((ext_vector_type(4))) unsigned short ushortx4;

__device__ __forceinline__ uint16_t f32_to_bf16(float x) {
    union { float f; uint32_t u; } v; v.f = x;
    return (uint16_t)((v.u + 0x7FFFu + ((v.u >> 16) & 1u)) >> 16);
}

// Direct HBM -> LDS DMA, 16 B per lane. LDS dest is wave-uniform base
// (hardware adds lane*16B); global src is per-lane.
__device__ __forceinline__ void gload_lds16(const uint16_t* g, short* l) {
    __builtin_amdgcn_global_load_lds(
        (const __attribute__((address_space(1))) void*)g,
        (__attribute__((address_space(3))) void*)l,
        16, 0, 0);
}

// counted-vmcnt wait: loads stay in flight across barriers (T4)
#define WAITV(n) asm volatile("s_waitcnt vmcnt(" #n ")" ::: "memory")
// full fence barrier: sched_barrier on BOTH sides so no memory op (incl.
// global_load_lds) migrates across the s_barrier (m152 race class).
#define BARRIER() do { __builtin_amdgcn_sched_barrier(0); \
                       __builtin_amdgcn_s_barrier(); \
                       __builtin_amdgcn_sched_barrier(0); } while (0)

// ---------------------------------------------------------------- zero dsum
__global__ void k_zero(float* __restrict__ p) {
    int i = blockIdx.x * 256 + threadIdx.x;
    if (i < N_ * M_) p[i] = 0.f;
}

// ---------------------------------------------------------------- q_val copy (channels 0..511)
__global__ __launch_bounds__(256) void k_copy_qval(const float* __restrict__ qv,
                                                   float* __restrict__ out) {
    unsigned i = blockIdx.x * 256 + threadIdx.x;
    unsigned e = i * 4u;
    unsigned n = e / (CV * HW);
    unsigned off = e - n * (CV * HW);
    *(floatx4*)&out[(size_t)n * (2 * CV * HW) + off] = *(const floatx4*)&qv[e];
}

// ---------------------------------------------------------------- transpose [N][CK][L] fp32 -> [N][L][CK] bf16
__global__ __launch_bounds__(256) void k_trans(const float* __restrict__ in,
                                               uint16_t* __restrict__ outp, int L) {
    __shared__ float tile[32][33];
    const int tx = threadIdx.x & 31;
    const int ty = threadIdx.x >> 5;      // 0..7
    const int l0 = blockIdx.x * 32;
    const int c0 = blockIdx.y * 32;
    const int n  = blockIdx.z;
    const float* src = in + (size_t)n * CK * L;
    uint16_t* dst = outp + (size_t)n * L * CK;
#pragma unroll
    for (int p = 0; p < 4; p++) {
        int c = c0 + p * 8 + ty;
        int l = l0 + tx;
        float v = 0.f;
        if (l < L) v = src[(size_t)c * L + l];
        tile[p * 8 + ty][tx] = v;
    }
    __syncthreads();
#pragma unroll
    for (int p = 0; p < 4; p++) {
        int l = l0 + p * 8 + ty;
        int c = c0 + tx;
        if (l < L) dst[(size_t)l * CK + c] = f32_to_bf16(tile[tx][p * 8 + ty]);
    }
}

// ---------------------------------------------------------------- K1: aff = qkT mkT^T, exp, colsum
// Counted-vmcnt 4-buffer pipeline (BK=32, prefetch depth 3): raw s_barrier +
// asm vmcnt(N); loads stay in flight across barriers (T4). Linear [128][32]
// tiles, 64B row stride (dense b128 reads). 64KB staging reused as the
// 128x144 C-tile in the epilogue (C-tile = smem[0..18431]; last compute
// buffer is buf3 at [24576..32767] -> disjoint).
#define K1_TS 144   // C-tile stride (shorts)

__global__ __launch_bounds__(256) void k1_gemm_exp(
    const uint16_t* __restrict__ qkT,  // [N][HW][CK] bf16 (A: rows q, k=c)
    const uint16_t* __restrict__ mkT,  // [N][M][CK] bf16  (B: rows m, k=c)
    uint16_t* __restrict__ E,          // [N][HW][M] bf16 = exp(aff*scale)
    float* __restrict__ dsum)          // [N][M]
{
    __shared__ __align__(16) short smem[32768];   // 4 bufs x (A 4096 + B 4096)
    __shared__ float colsum[128];

    // XCD swizzle: 3648 blocks, 456/XCD = exactly one n-plane per XCD.
    const int bid = blockIdx.x + 57 * (blockIdx.y + 8 * blockIdx.z);
    const int swz = (bid & 7) * 456 + (bid >> 3);
    const int mb   = swz % 57;
    const int rest = swz / 57;
    const int m0 = mb * 128;
    const int q0 = (rest & 7) * 128;
    const int n  = rest >> 3;
    const int tid = threadIdx.x;

    if (tid < 128) colsum[tid] = 0.f;

    const int lane = tid & 63;
    const int wid  = tid >> 6;
    const int wq   = (wid >> 1) << 6;
    const int wm   = (wid & 1) << 6;
    const int fr   = lane & 15;
    const int quad = lane >> 4;

    // staging geometry: 8 chunks/operand of 1KB (16 rows x 32 cols bf16);
    // wave wid owns chunks {2*wid, 2*wid+1} of A and of B.
    const int ca = wid * 2;
    const int rr = lane >> 2;        // row within chunk 0..15
    const int cc = (lane & 3) * 8;   // col (shorts), 16B aligned

    const uint16_t* Ab = qkT + (size_t)n * HW * CK;
    const uint16_t* Bb = mkT + (size_t)n * M_ * CK;
    const uint16_t* A0p = Ab + (size_t)(q0 + ca * 16 + rr) * CK + cc;
    const uint16_t* A1p = A0p + 16 * CK;
    const uint16_t* B0p = Bb + (size_t)(m0 + ca * 16 + rr) * CK + cc;
    const uint16_t* B1p = B0p + 16 * CK;

    floatx4 acc[4][4];
#pragma unroll
    for (int a = 0; a < 4; a++)
#pragma unroll
        for (int b = 0; b < 4; b++) acc[a][b] = (floatx4){0.f, 0.f, 0.f, 0.f};

#define K1_STAGE(buf, ko) do { \
    short* dA = smem + (buf) * 8192 + ca * 512; \
    short* dB = dA + 4096; \
    gload_lds16(A0p + (ko), dA); \
    gload_lds16(A1p + (ko), dA + 512); \
    gload_lds16(B0p + (ko), dB); \
    gload_lds16(B1p + (ko), dB + 512); \
} while (0)

#define K1_COMPUTE(buf) do { \
    const short* bA = smem + (buf) * 8192; \
    const short* bB = bA + 4096; \
    const int k0 = quad * 8; \
    short8 af[4], bfr[4]; \
    _Pragma("unroll") \
    for (int t = 0; t < 4; t++) \
        af[t] = *(const short8*)&bA[(wq + t * 16 + fr) * 32 + k0]; \
    _Pragma("unroll") \
    for (int t = 0; t < 4; t++) \
        bfr[t] = *(const short8*)&bB[(wm + t * 16 + fr) * 32 + k0]; \
    _Pragma("unroll") \
    for (int tq = 0; tq < 4; tq++) \
        _Pragma("unroll") \
        for (int tm = 0; tm < 4; tm++) \
            acc[tq][tm] = __builtin_amdgcn_mfma_f32_16x16x32_bf16( \
                af[tq], bfr[tm], acc[tq][tm], 0, 0, 0); \
} while (0)

    // prefetch depth 3 over 4 K-steps (CK=128, BK=32)
    K1_STAGE(0, 0); K1_STAGE(1, 32); K1_STAGE(2, 64);
    WAITV(8); BARRIER(); K1_STAGE(3, 96); K1_COMPUTE(0);   // t=0
    WAITV(8); BARRIER(); K1_COMPUTE(1);                    // t=1
    WAITV(4); BARRIER(); K1_COMPUTE(2);                    // t=2
    WAITV(0); BARRIER(); K1_COMPUTE(3);                    // t=3

    // ---- epilogue phase A: exp -> LDS C-tile (stride 144), colsum
    __syncthreads();   // all frag reads done; smem reusable as C-tile
    float cs[4] = {0.f, 0.f, 0.f, 0.f};
#pragma unroll
    for (int tq = 0; tq < 4; tq++) {
#pragma unroll
        for (int tm = 0; tm < 4; tm++) {
            const int col = wm + tm * 16 + fr;
#pragma unroll
            for (int i = 0; i < 4; i++) {
                const int row = wq + tq * 16 + quad * 4 + i;
                float e = __expf(acc[tq][tm][i] * QK_SCALE);
                if (q0 + row < HW) cs[tm] += e;   // guard: padded q-rows must not pollute colsum
                smem[row * K1_TS + col] = (short)f32_to_bf16(e);
            }
        }
    }
#pragma unroll
    for (int tm = 0; tm < 4; tm++) {
        float s = cs[tm];
        s += __shfl_xor(s, 16, 64);
        s += __shfl_xor(s, 32, 64);
        if (quad == 0) atomicAdd(&colsum[wm + tm * 16 + fr], s);
    }
    __syncthreads();   // C-tile complete + colsum complete

    // ---- epilogue phase B: coalesced uint4 E-writes (8 per thread)
    uint16_t* En = E + (size_t)n * HW * M_;
#pragma unroll
    for (int j = 0; j < 8; j++) {
        int idx = tid + j * 256;       // 0..2047 = 128 rows x 16 uint4
        int r   = idx >> 4;
        int c8  = (idx & 15) * 8;      // short offset in row
        if (q0 + r < HW && m0 + c8 + 8 <= M_) {
            uintx4 v = *(const uintx4*)&smem[r * K1_TS + c8];
            *(uintx4*)&En[(size_t)(q0 + r) * M_ + m0 + c8] = v;
        }
    }
    if (tid < 128) {
        const int gm = m0 + tid;
        if (gm < M_) atomicAdd(&dsum[(size_t)n * M_ + gm], colsum[tid]);
    }
#undef K1_STAGE
#undef K1_COMPUTE
}

// ---------------------------------------------------------------- dinv = 1/d
__global__ void k_dinv(const float* __restrict__ d, float* __restrict__ di) {
    int i = blockIdx.x * 256 + threadIdx.x;
    if (i < N_ * M_) di[i] = 1.0f / d[i];
}

// ---------------------------------------------------------------- mvs = bf16(mv * dinv[m])
__global__ __launch_bounds__(256) void k_mvs(
    const float* __restrict__ mval,   // [N][CV][M]
    const float* __restrict__ dinv,   // [N][M]
    uint16_t* __restrict__ mvs)       // [N][CV][M]
{
    unsigned i = blockIdx.x * 256 + threadIdx.x;
    unsigned base = i * 4u;
    unsigned n = base / (unsigned)(CV * M_);
    unsigned m = base % (unsigned)M_;
    floatx4 v  = *(const floatx4*)&mval[base];
    floatx4 di = *(const floatx4*)&dinv[n * (unsigned)M_ + m];
    ushortx4 o;
    o[0] = f32_to_bf16(v[0] * di[0]);
    o[1] = f32_to_bf16(v[1] * di[1]);
    o[2] = f32_to_bf16(v[2] * di[2]);
    o[3] = f32_to_bf16(v[3] * di[3]);
    *(ushortx4*)&mvs[base] = o;
}

// ---------------------------------------------------------------- K2 split x3
// Counted-vmcnt 4-buffer ring (BK=32, prefetch depth 3). Per iter:
// vmcnt(8) [t+1,t+2 stay in flight] -> s_barrier -> issue stage t+3 ->
// MFMA tile t. Stage t+3 overwrites buf[(t+3)&3] = buf[(t-1)&3], whose
// last ds_reads were issued+drained (lgkmcnt before MFMA use) before this
// iter's barrier in every wave (WAR-safe).
#define K2_SPLITS 3
#define K2_BK 32
#define K2_STEPS 75   // 2400 / 32

__global__ __launch_bounds__(256) void k2_split3(
    const uint16_t* __restrict__ mvs,  // [N][CV][M] bf16
    const uint16_t* __restrict__ E,    // [N][HW][M] bf16
    float* __restrict__ partials)      // [3][N][CV][HW]
{
    __shared__ __align__(16) short lds2[32768];   // 4 bufs x (A 4096 + B 4096)

    // XCD swizzle: 768 blocks, 96/XCD (bijective); consecutive ids share
    // (n,split) planes -> E/mvs panel reuse lands in the same L2.
    const int bid = blockIdx.x + 8 * (blockIdx.y + 4 * blockIdx.z);
    const int swz = (bid & 7) * 96 + (bid >> 3);
    const int q0 = (swz & 7) << 7;
    const int c0 = ((swz >> 3) & 3) << 7;
    const int nz = swz >> 5;
    const int n     = nz / K2_SPLITS;
    const int split = nz - n * K2_SPLITS;
    const int tid = threadIdx.x;

    const int lane = tid & 63;
    const int wid  = tid >> 6;
    const int wc   = (wid >> 1) << 6;
    const int wq   = (wid & 1) << 6;
    const int fr   = lane & 15;
    const int quad = lane >> 4;

    // staging geometry: 8 chunks/operand of 1KB (16 rows x 32 cols bf16);
    // wave wid owns chunks {2*wid, 2*wid+1} of A and of B.
    const int ca = wid * 2;
    const int rr = lane >> 2;
    const int cc = (lane & 3) * 8;

    const uint16_t* Asrc = mvs + (size_t)(n * CV + c0) * M_ + split * 2400;
    const uint16_t* Bsrc = E + (size_t)n * HW * M_ + split * 2400;
    const uint16_t* A0p = Asrc + (size_t)(ca * 16 + rr) * M_ + cc;
    const uint16_t* A1p = A0p + (size_t)16 * M_;
    const uint16_t* B0p = Bsrc + (size_t)(q0 + ca * 16 + rr) * M_ + cc;
    const uint16_t* B1p = B0p + (size_t)16 * M_;

    floatx4 acc[4][4];
#pragma unroll
    for (int a = 0; a < 4; a++)
#pragma unroll
        for (int b = 0; b < 4; b++) acc[a][b] = (floatx4){0.f, 0.f, 0.f, 0.f};

#define K2_STAGE(buf, mo) do { \
    short* dA = lds2 + (buf) * 8192 + ca * 512; \
    short* dB = dA + 4096; \
    gload_lds16(A0p + (mo), dA); \
    gload_lds16(A1p + (mo), dA + 512); \
    gload_lds16(B0p + (mo), dB); \
    gload_lds16(B1p + (mo), dB + 512); \
} while (0)

#define K2_COMPUTE(buf) do { \
    const short* bA = lds2 + (buf) * 8192; \
    const short* bB = bA + 4096; \
    const int k0 = quad * 8; \
    short8 af[4], bfr[4]; \
    _Pragma("unroll") \
    for (int t = 0; t < 4; t++) \
        af[t] = *(const short8*)&bA[(wc + t * 16 + fr) * 32 + k0]; \
    _Pragma("unroll") \
    for (int t = 0; t < 4; t++) \
        bfr[t] = *(const short8*)&bB[(wq + t * 16 + fr) * 32 + k0]; \
    _Pragma("unroll") \
    for (int tc = 0; tc < 4; tc++) \
        _Pragma("unroll") \
        for (int tq = 0; tq < 4; tq++) \
            acc[tc][tq] = __builtin_amdgcn_mfma_f32_16x16x32_bf16( \
                af[tc], bfr[tq], acc[tc][tq], 0, 0, 0); \
} while (0)

    K2_STAGE(0, 0);
    K2_STAGE(1, K2_BK);
    K2_STAGE(2, 2 * K2_BK);
    for (int t = 0; t < K2_STEPS - 3; ++t) {      // t = 0..71
        WAITV(8); BARRIER();
        K2_STAGE((t + 3) & 3, (t + 3) * K2_BK);
        K2_COMPUTE(t & 3);
    }
    WAITV(8); BARRIER(); K2_COMPUTE(0);           // t=72 (72&3==0)
    WAITV(4); BARRIER(); K2_COMPUTE(1);           // t=73
    WAITV(0); BARRIER(); K2_COMPUTE(2);           // t=74

    float* P = partials + ((size_t)split * N_ + n) * CV * HW;
#pragma unroll
    for (int tc = 0; tc < 4; tc++) {
#pragma unroll
        for (int tq = 0; tq < 4; tq++) {
            const int gq = q0 + wq + tq * 16 + fr;
            if (gq < HW) {
#pragma unroll
                for (int i = 0; i < 4; i++) {
                    const int gc = c0 + wc + tc * 16 + quad * 4 + i;
                    P[(size_t)gc * HW + gq] = acc[tc][tq][i];
                }
            }
        }
    }
#undef K2_STAGE
#undef K2_COMPUTE
}

// ---------------------------------------------------------------- reduce 3 partials -> out mapped half
__global__ __launch_bounds__(256) void k_reduce3(const float* __restrict__ partials,
                                                 float* __restrict__ out) {
    unsigned i = blockIdx.x * 256 + threadIdx.x;
    unsigned e = i * 4u;
    unsigned n = e / (CV * HW);
    unsigned off = e - n * (CV * HW);
    const size_t stride = (size_t)N_ * CV * HW;
    const float* p = partials + (size_t)n * CV * HW + off;
    floatx4 a = *(const floatx4*)&p[0];
    floatx4 b = *(const floatx4*)&p[stride];
    floatx4 c = *(const floatx4*)&p[2 * stride];
    floatx4 s = a + b + c;
    *(floatx4*)&out[(size_t)n * (2 * CV * HW) + CV * HW + off] = s;
}

// ----------------------------------------------------------------
extern "C" void kernel_launch(void* const* d_in, const int* in_sizes, int n_in,
                              void* d_out, int out_size, void* d_ws, size_t ws_size,
                              hipStream_t stream) {
    const float* qkey = (const float*)d_in[0];  // [8][128][900]
    const float* qval = (const float*)d_in[1];  // [8][512][900]
    const float* mkey = (const float*)d_in[2];  // [8][128][7200]
    const float* mval = (const float*)d_in[3];  // [8][512][7200]
    float* out = (float*)d_out;                 // [8][1024][900]

    char* ws = (char*)d_ws;
    // E 103,680,000 | dsum 230,400 | dinv 230,400 | mvs 58,982,400 | partials 44,236,800 = 207,360,000
    // qkT/mkT alias partials (dead before k2_split3 writes partials).
    uint16_t* E        = (uint16_t*)ws;
    float*    dsum     = (float*)(ws + 103680000);
    float*    dinv     = (float*)(ws + 103910400);
    uint16_t* mvs      = (uint16_t*)(ws + 104140800);
    float*    partials = (float*)(ws + 163123200);
    uint16_t* qkT      = (uint16_t*)(ws + 163123200);
    uint16_t* mkT      = (uint16_t*)(ws + 163123200 + 1843200);

    (void)in_sizes; (void)n_in; (void)out_size; (void)ws_size;

    k_zero<<<dim3((N_ * M_ + 255) / 256), 256, 0, stream>>>(dsum);
    k_copy_qval<<<dim3((N_ * CV * HW) / 4 / 256), 256, 0, stream>>>(qval, out);
    k_trans<<<dim3(29, 4, N_), 256, 0, stream>>>(qkey, qkT, HW);
    k_trans<<<dim3(225, 4, N_), 256, 0, stream>>>(mkey, mkT, M_);
    k1_gemm_exp<<<dim3(57, 8, N_), 256, 0, stream>>>(qkT, mkT, E, dsum);
    k_dinv<<<dim3((N_ * M_ + 255) / 256), 256, 0, stream>>>(dsum, dinv);
    k_mvs<<<dim3((N_ * CV * M_) / 4 / 256), 256, 0, stream>>>(mval, dinv, mvs);
    k2_split3<<<dim3(8, 4, N_ * K2_SPLITS), 256, 0, stream>>>(mvs, E, partials);
    k_reduce3<<<dim3((N_ * CV * HW) / 4 / 256), 256, 0, stream>>>(partials, out);
}